// Round 1
// baseline (421.989 us; speedup 1.0000x reference)
//
#include <hip/hip_runtime.h>
#include <stdint.h>

#define DEV __device__ __forceinline__

typedef __bf16 bf16x8 __attribute__((ext_vector_type(8)));
typedef float  f32x4  __attribute__((ext_vector_type(4)));
typedef unsigned short us8 __attribute__((ext_vector_type(8)));

DEV unsigned short f2bf(float f) {
  union { float f; uint32_t u; } v; v.f = f;
  uint32_t u = v.u;
  return (unsigned short)((u + 0x7FFFu + ((u >> 16) & 1u)) >> 16);
}
DEV float bf2f(unsigned short h) {
  union { uint32_t u; float f; } v; v.u = ((uint32_t)h) << 16;
  return v.f;
}

// async global->LDS, 16B per lane; LDS dest must be linear (base + lane*16)
#define GLOAD16(gp, lp) __builtin_amdgcn_global_load_lds( \
    (__attribute__((address_space(1))) void*)(gp),        \
    (__attribute__((address_space(3))) void*)(lp), 16, 0, 0)

// ---------------- fp32 -> bf16 conversion (vectorized) ----------------
__global__ void cvt_f32_bf16(const float* __restrict__ in,
                             unsigned short* __restrict__ out, int n4) {
  int i = blockIdx.x * blockDim.x + threadIdx.x;
  const int stride = gridDim.x * blockDim.x;
  for (; i < n4; i += stride) {
    float4 f = reinterpret_cast<const float4*>(in)[i];
    ushort4 o;
    o.x = f2bf(f.x); o.y = f2bf(f.y); o.z = f2bf(f.z); o.w = f2bf(f.w);
    reinterpret_cast<ushort4*>(out)[i] = o;
  }
}

// ---------------- bf16 GEMM: C = A * Bt^T  (A:[M,K], Bt:[N,K], both row-major)
// MODE 0: C bf16 [M,N] row-major
// MODE 1: C bf16 written V-transposed: [b,h,d,s] = [4,16,64,2048]
// MODE 2: C fp32 [M,N] row-major
template<int MODE>
__global__ __launch_bounds__(256, 2) void gemm_bt(
    const unsigned short* __restrict__ A,
    const unsigned short* __restrict__ Bt,
    void* __restrict__ Cout, int M, int N, int K)
{
  __shared__ __align__(16) unsigned short As[128 * 32];
  __shared__ __align__(16) unsigned short Bs[128 * 32];
  const int t    = threadIdx.x;
  const int lane = t & 63;
  const int w    = t >> 6;
  const int wm   = w >> 1, wn = w & 1;     // 2x2 wave grid, 64x64 per wave
  const int brow = blockIdx.y * 128;
  const int bcol = blockIdx.x * 128;
  const int lr   = lane & 15;              // fragment row/col within 16
  const int lk   = lane >> 4;              // k-group (0..3) -> k offset *8
  const int srow = t >> 2;                 // staging row 0..63 (per pass)
  const int scol = (t & 3) * 8;            // staging k offset 0/8/16/24

  f32x4 acc[4][4] = {};

  for (int kt = 0; kt < K; kt += 32) {
    __syncthreads();  // protect previous iteration's LDS reads
    GLOAD16(A  + (size_t)(brow + srow)      * K + kt + scol, As + t * 8);
    GLOAD16(A  + (size_t)(brow + 64 + srow) * K + kt + scol, As + 2048 + t * 8);
    GLOAD16(Bt + (size_t)(bcol + srow)      * K + kt + scol, Bs + t * 8);
    GLOAD16(Bt + (size_t)(bcol + 64 + srow) * K + kt + scol, Bs + 2048 + t * 8);
    __syncthreads();  // compiler emits vmcnt(0) drain here

    bf16x8 af[4], bfr[4];
#pragma unroll
    for (int mi = 0; mi < 4; ++mi)
      af[mi] = *reinterpret_cast<const bf16x8*>(As + (wm * 64 + mi * 16 + lr) * 32 + lk * 8);
#pragma unroll
    for (int ni = 0; ni < 4; ++ni)
      bfr[ni] = *reinterpret_cast<const bf16x8*>(Bs + (wn * 64 + ni * 16 + lr) * 32 + lk * 8);
#pragma unroll
    for (int mi = 0; mi < 4; ++mi)
#pragma unroll
      for (int ni = 0; ni < 4; ++ni)
        acc[mi][ni] = __builtin_amdgcn_mfma_f32_16x16x32_bf16(af[mi], bfr[ni], acc[mi][ni], 0, 0, 0);
  }

  // epilogue: C/D layout col=lane&15, row=(lane>>4)*4+reg
#pragma unroll
  for (int mi = 0; mi < 4; ++mi) {
    const int row0 = brow + wm * 64 + mi * 16 + lk * 4;
#pragma unroll
    for (int ni = 0; ni < 4; ++ni) {
      const int col = bcol + wn * 64 + ni * 16 + lr;
#pragma unroll
      for (int rr = 0; rr < 4; ++rr) {
        const int row = row0 + rr;
        const float vv = acc[mi][ni][rr];
        if (MODE == 0) {
          ((unsigned short*)Cout)[(size_t)row * N + col] = f2bf(vv);
        } else if (MODE == 2) {
          ((float*)Cout)[(size_t)row * N + col] = vv;
        } else {  // V transposed: [b,h,d,s]
          const int bb = row >> 11, ss = row & 2047;
          const int hh = col >> 6,  dd = col & 63;
          ((unsigned short*)Cout)[(size_t)((bb * 16 + hh) * 64 + dd) * 2048 + ss] = f2bf(vv);
        }
      }
    }
  }
}

// ---------------- flash-style attention ----------------
// Q,K: bf16 [8192,1024] (row = b*2048+s, col = h*64+d); Vt: bf16 [b,h,d,s]
// O: bf16 [8192,1024]. Per block: one (b,h,128-q-row tile); 4 waves x 32 rows.
__global__ __launch_bounds__(256, 2) void attn_fwd(
    const unsigned short* __restrict__ Q,
    const unsigned short* __restrict__ Kg,
    const unsigned short* __restrict__ Vt,
    unsigned short* __restrict__ O)
{
  __shared__ __align__(16) unsigned short Kl[64 * 72];     // [kv=64][d=64]+pad
  __shared__ __align__(16) unsigned short Vl[64 * 72];     // [d=64][kv=64]+pad
  __shared__ __align__(16) unsigned short Pl[4][32 * 72];  // per-wave P tile
  const int t    = threadIdx.x;
  const int lane = t & 63;
  const int w    = t >> 6;
  const int lr   = lane & 15;
  const int lk   = lane >> 4;
  const int h    = blockIdx.y;
  const int b    = blockIdx.z;
  const int q0   = blockIdx.x * 128 + w * 32;
  const size_t qrow0 = (size_t)b * 2048 + q0;

  // Q fragments, pre-scaled by 1/sqrt(64)=0.125 (exact in bf16)
  bf16x8 qf[2][2];
#pragma unroll
  for (int m16 = 0; m16 < 2; ++m16)
#pragma unroll
    for (int kk = 0; kk < 2; ++kk) {
      us8 raw = *reinterpret_cast<const us8*>(
          Q + (qrow0 + m16 * 16 + lr) * 1024 + h * 64 + kk * 32 + lk * 8);
      union { bf16x8 v; unsigned short u[8]; } tmp;
#pragma unroll
      for (int j = 0; j < 8; ++j) tmp.u[j] = f2bf(bf2f(raw[j]) * 0.125f);
      qf[m16][kk] = tmp.v;
    }

  f32x4 oacc[2][4] = {};
  float rmax[2][4], rsum[2][4];
#pragma unroll
  for (int i = 0; i < 2; ++i)
#pragma unroll
    for (int j = 0; j < 4; ++j) { rmax[i][j] = -1e30f; rsum[i][j] = 0.f; }

  const unsigned short* Kbase = Kg + (size_t)b * 2048 * 1024 + h * 64;
  const unsigned short* Vbase = Vt + (size_t)((b * 16 + h) * 64) * 2048;
  const int sr = t >> 3;        // staging row 0..31 per pass
  const int sc = (t & 7) * 8;   // staging col offset

  for (int kv0 = 0; kv0 < 2048; kv0 += 64) {
    __syncthreads();  // prior tile's LDS reads done
#pragma unroll
    for (int pass = 0; pass < 2; ++pass) {
      const int row = pass * 32 + sr;
      *reinterpret_cast<us8*>(&Kl[row * 72 + sc]) =
          *reinterpret_cast<const us8*>(Kbase + (size_t)(kv0 + row) * 1024 + sc);
      *reinterpret_cast<us8*>(&Vl[row * 72 + sc]) =
          *reinterpret_cast<const us8*>(Vbase + (size_t)row * 2048 + kv0 + sc);
    }
    __syncthreads();  // staging visible

    // S = Q K^T  (scaled via Q)
    bf16x8 kf[4][2];
#pragma unroll
    for (int ni = 0; ni < 4; ++ni)
#pragma unroll
      for (int kk = 0; kk < 2; ++kk)
        kf[ni][kk] = *reinterpret_cast<const bf16x8*>(&Kl[(ni * 16 + lr) * 72 + kk * 32 + lk * 8]);

    f32x4 sacc[2][4] = {};
#pragma unroll
    for (int m16 = 0; m16 < 2; ++m16)
#pragma unroll
      for (int ni = 0; ni < 4; ++ni)
#pragma unroll
        for (int kk = 0; kk < 2; ++kk)
          sacc[m16][ni] = __builtin_amdgcn_mfma_f32_16x16x32_bf16(qf[m16][kk], kf[ni][kk], sacc[m16][ni], 0, 0, 0);

    // online softmax: rows live at (lk*4+rr), cols at (ni*16+lr)
#pragma unroll
    for (int m16 = 0; m16 < 2; ++m16) {
#pragma unroll
      for (int rr = 0; rr < 4; ++rr) {
        float mx = fmaxf(fmaxf(sacc[m16][0][rr], sacc[m16][1][rr]),
                         fmaxf(sacc[m16][2][rr], sacc[m16][3][rr]));
        mx = fmaxf(mx, __shfl_xor(mx, 1));
        mx = fmaxf(mx, __shfl_xor(mx, 2));
        mx = fmaxf(mx, __shfl_xor(mx, 4));
        mx = fmaxf(mx, __shfl_xor(mx, 8));
        const float mold = rmax[m16][rr];
        const float mnew = fmaxf(mold, mx);
        const float corr = __expf(mold - mnew);
        rmax[m16][rr] = mnew;
        float psum = 0.f;
#pragma unroll
        for (int ni = 0; ni < 4; ++ni) {
          const float p = __expf(sacc[m16][ni][rr] - mnew);
          sacc[m16][ni][rr] = p;
          psum += p;
        }
        psum += __shfl_xor(psum, 1);
        psum += __shfl_xor(psum, 2);
        psum += __shfl_xor(psum, 4);
        psum += __shfl_xor(psum, 8);
        rsum[m16][rr] = rsum[m16][rr] * corr + psum;
#pragma unroll
        for (int d16 = 0; d16 < 4; ++d16) oacc[m16][d16][rr] *= corr;
        const int prow = m16 * 16 + lk * 4 + rr;
#pragma unroll
        for (int ni = 0; ni < 4; ++ni)
          Pl[w][prow * 72 + ni * 16 + lr] = f2bf(sacc[m16][ni][rr]);
      }
    }

    // same-wave LDS write->read fence (P tile is per-wave private)
    asm volatile("s_waitcnt lgkmcnt(0)" ::: "memory");
    __builtin_amdgcn_sched_barrier(0);

    // O += P V
#pragma unroll
    for (int kk = 0; kk < 2; ++kk) {
      bf16x8 vf[4];
#pragma unroll
      for (int d16 = 0; d16 < 4; ++d16)
        vf[d16] = *reinterpret_cast<const bf16x8*>(&Vl[(d16 * 16 + lr) * 72 + kk * 32 + lk * 8]);
#pragma unroll
      for (int m16 = 0; m16 < 2; ++m16) {
        const bf16x8 pf = *reinterpret_cast<const bf16x8*>(&Pl[w][(m16 * 16 + lr) * 72 + kk * 32 + lk * 8]);
#pragma unroll
        for (int d16 = 0; d16 < 4; ++d16)
          oacc[m16][d16] = __builtin_amdgcn_mfma_f32_16x16x32_bf16(pf, vf[d16], oacc[m16][d16], 0, 0, 0);
      }
    }
  }

  // normalize + store bf16
#pragma unroll
  for (int m16 = 0; m16 < 2; ++m16)
#pragma unroll
    for (int rr = 0; rr < 4; ++rr) {
      const float inv = 1.f / rsum[m16][rr];
      const size_t row = qrow0 + m16 * 16 + lk * 4 + rr;
#pragma unroll
      for (int d16 = 0; d16 < 4; ++d16)
        O[row * 1024 + h * 64 + d16 * 16 + lr] = f2bf(oacc[m16][d16][rr] * inv);
    }
}

// ---------------- launch ----------------
extern "C" void kernel_launch(void* const* d_in, const int* in_sizes, int n_in,
                              void* d_out, int out_size, void* d_ws, size_t ws_size,
                              hipStream_t stream) {
  const float* x  = (const float*)d_in[0];
  const float* wq = (const float*)d_in[1];
  const float* wk = (const float*)d_in[2];
  const float* wv = (const float*)d_in[3];
  const float* wo = (const float*)d_in[4];
  float* out = (float*)d_out;
  uint8_t* ws = (uint8_t*)d_ws;
  const size_t MB = 1024 * 1024;
  // ws layout (72 MB total): xb reused as attention-output buffer
  unsigned short* xb  = (unsigned short*)(ws + 0);        // 16MB x bf16 / attnO
  unsigned short* wqb = (unsigned short*)(ws + 16 * MB);  // 2MB
  unsigned short* wkb = (unsigned short*)(ws + 18 * MB);
  unsigned short* wvb = (unsigned short*)(ws + 20 * MB);
  unsigned short* wob = (unsigned short*)(ws + 22 * MB);
  unsigned short* Qb  = (unsigned short*)(ws + 24 * MB);  // 16MB
  unsigned short* Kb  = (unsigned short*)(ws + 40 * MB);  // 16MB
  unsigned short* Vtb = (unsigned short*)(ws + 56 * MB);  // 16MB
  unsigned short* Ob  = xb;  // alias: x dead after QKV GEMMs

  cvt_f32_bf16<<<2048, 256, 0, stream>>>(x,  xb,  (4 * 2048 * 1024) / 4);
  cvt_f32_bf16<<<512, 256, 0, stream>>>(wq, wqb, (1024 * 1024) / 4);
  cvt_f32_bf16<<<512, 256, 0, stream>>>(wk, wkb, (1024 * 1024) / 4);
  cvt_f32_bf16<<<512, 256, 0, stream>>>(wv, wvb, (1024 * 1024) / 4);
  cvt_f32_bf16<<<512, 256, 0, stream>>>(wo, wob, (1024 * 1024) / 4);

  dim3 gg(1024 / 128, 8192 / 128);
  gemm_bt<0><<<gg, 256, 0, stream>>>(xb, wqb, Qb,  8192, 1024, 1024);
  gemm_bt<0><<<gg, 256, 0, stream>>>(xb, wkb, Kb,  8192, 1024, 1024);
  gemm_bt<1><<<gg, 256, 0, stream>>>(xb, wvb, Vtb, 8192, 1024, 1024);

  attn_fwd<<<dim3(16, 16, 4), 256, 0, stream>>>(Qb, Kb, Vtb, Ob);

  gemm_bt<2><<<gg, 256, 0, stream>>>(Ob, wob, out, 8192, 1024, 1024);
}